// Round 8
// baseline (888.990 us; speedup 1.0000x reference)
//
#include <hip/hip_runtime.h>

// Seq2SeqWithAlignment: enc/dec LSTM -> hpre -> logits logsumexp -> Viterbi align.
// K=64 enc steps, T=128 dec tokens (127 dec steps used), H=512, E=100, V=32000.

#define K_ENC 64
#define HID   512
#define EMB   100
#define VOC   32000
#define G4    2048   // 4*HID

typedef __attribute__((ext_vector_type(8))) short  short8;
typedef __attribute__((ext_vector_type(4))) float  f32x4;

#define LOG2E 1.4426950408889634f
#define LN2   0.6931471805599453f

__device__ __forceinline__ unsigned short f2bf(float f) {
  union { float f; unsigned u; } x; x.f = f;
  unsigned r = x.u + 0x7FFFu + ((x.u >> 16) & 1u);  // RNE
  return (unsigned short)(r >> 16);
}
__device__ __forceinline__ float bf2f(unsigned short s) {
  union { unsigned u; float f; } x; x.u = ((unsigned)s) << 16; return x.f;
}

__device__ __forceinline__ float fast_sigmoid(float x) {
  return __builtin_amdgcn_rcpf(1.f + __builtin_amdgcn_exp2f(-LOG2E * x));
}
__device__ __forceinline__ float fast_tanh(float x) {
  return 1.f - 2.f * __builtin_amdgcn_rcpf(1.f + __builtin_amdgcn_exp2f(2.f * LOG2E * x));
}

// ---------------- workspace layout (float offsets) ----------------
#define OFF_PAD   0         // 256 floats: unused
#define OFF_HBUF  256       // 4096 floats = 2048 u64: tagged h channels [grp][slot][512]
#define OFF_G0E   4352      // 64*2048  : enc Wih@x + bih + bhh
#define OFF_G0D   135424    // 127*2048 : dec
#define OFF_EENC  395520    // 64*512
#define OFF_D     428288    // 127*512
#define OFF_EWE   493312    // 64*100   : log2e * Eenc@We_E^T
#define OFF_DWD   499712    // 127*100  : log2e * (D@We_D^T + beh)
#define OFF_BEM   512412    // 32000    : log2e * bem
#define OFF_SUM   544412    // 127*64   : sum of 2^s over v (atomic)
#define OFF_EM    552540    // 127*64   : emission
#define OFF_WEM   560668    // ushort[4096000]: Wem bf16 in MFMA-B fragment-linear layout
// total ~10.4 MB

// ---------------- zero init (tagged h channels => tag 0 / value 0, sumexp) ----------------
__global__ void kZero(float* __restrict__ ws) {
  int gid = blockIdx.x * 256 + threadIdx.x;
  if (gid < 4352) ws[gid] = 0.f;
  else if (gid < 4352 + 127 * 64) ws[OFF_SUM + gid - 4352] = 0.f;
}

// ---------------- G0 = Wih @ emb[tok] + bih + bhh ----------------
__global__ __launch_bounds__(256) void kG0(const int* __restrict__ x, const int* __restrict__ y,
                    const float* __restrict__ emb,
                    const float* __restrict__ eWih, const float* __restrict__ ebih,
                    const float* __restrict__ ebhh,
                    const float* __restrict__ dWih, const float* __restrict__ dbih,
                    const float* __restrict__ dbhh,
                    float* __restrict__ ws) {
  int gid = blockIdx.x * 256 + threadIdx.x;
  const int enc_total = K_ENC * G4;
  if (gid >= enc_total + 127 * G4) return;
  bool enc = gid < enc_total;
  int loc = enc ? gid : gid - enc_total;
  int t = loc >> 11, r = loc & (G4 - 1);
  int tok = enc ? x[t] : y[t];
  const float* Wr = (enc ? eWih : dWih) + r * EMB;
  const float* er = emb + tok * EMB;
  float s = 0.f;
  #pragma unroll 4
  for (int e = 0; e < EMB; ++e) s += er[e] * Wr[e];
  s += enc ? (ebih[r] + ebhh[r]) : (dbih[r] + dbhh[r]);
  ws[(enc ? OFF_G0E : OFF_G0D) + t * G4 + r] = s;
}

// ---------------- persistent LSTM (blocks 0..127) + fused WemPrep (blocks 128..255) ----
// LSTM: 64 WGs per group (grp = blk>>6), 8 j per WG, wave w owns j = wg*8 + w.
// All loop state in LDS: Whh slice bf16 (32KB), G0 slice fp32 (<=16.25KB), h bcast (2KB).
// R6/R7 lesson: compiler refuses VGPR-resident weights (VGPR stuck ~48-52 through
//   launch_bounds AND __restrict__) -> LDS residency is architectural, not heuristic.
// Sync (proven R5): producer atomicExch / wave0 atomicOr poll at coherence point,
//   LDS broadcast + one __syncthreads. Poll BOUNDED (no hang; fails finite).
// WemPrep fusion: blocks 128+ grid-stride the Wem->bf16 fragment swizzle + bem scale;
//   pure-BW work hidden under the latency-bound LSTM phase.
__global__ __launch_bounds__(512, 2) void kLstm(const float* __restrict__ eWhh,
                    const float* __restrict__ dWhh,
                    const float* __restrict__ Wem, const float* __restrict__ bem,
                    float* __restrict__ ws) {
  const int tid = threadIdx.x;
  if (blockIdx.x >= 128) {           // ---- fused WemPrep ----
    int b = blockIdx.x - 128;        // 0..127
    unsigned short* __restrict__ wdst = (unsigned short*)(ws + OFF_WEM);
    for (int gid = b * 512 + tid; gid < 4096000; gid += 128 * 512) {
      int vt = gid >> 11;
      int kb = (gid >> 9) & 3;
      int L  = (gid >> 3) & 63;
      int jj = gid & 7;
      int v = vt * 16 + (L & 15);
      int k = kb * 32 + ((L >> 4) << 3) + jj;
      float val = (k < EMB) ? Wem[v * EMB + k] : 0.f;
      wdst[gid] = f2bf(val);
      if (gid < VOC) ws[OFF_BEM + gid] = bem[gid] * LOG2E;
    }
    return;
  }
  const int grp = blockIdx.x >> 6;            // 0=enc, 1=dec
  const int wg  = blockIdx.x & 63;
  const float* __restrict__ Whh = grp ? dWhh : eWhh;
  const float* __restrict__ G0  = ws + (grp ? OFF_G0D : OFF_G0E);
  float* __restrict__ hs = ws + (grp ? OFF_D : OFF_EENC);
  unsigned long long* hb = (unsigned long long*)(ws + OFF_HBUF) + grp * 1024;  // [2][512]
  const int steps = grp ? 127 : K_ENC;
  const int w = tid >> 6, lane = tid & 63;
  const int j = wg * 8 + w;                   // owned h index (wave-per-j)
  __shared__ unsigned short w_bf[8 * 4 * 512];   // [jl][g][k] bf16, 32KB
  __shared__ float g0_lds[127 * 32];             // [t][g*8+jl] fp32, 16.25KB
  __shared__ float h_lds[512];                   // step-t h broadcast, 2KB
  // preload weight slice (bf16) and G0 slice
  for (int i = tid; i < 8 * 4 * 512; i += 512) {
    int jl = i >> 11, g = (i >> 9) & 3, k = i & 511;
    w_bf[i] = f2bf(Whh[(g * HID + wg * 8 + jl) * HID + k]);
  }
  for (int i = tid; i < steps * 32; i += 512) {
    int t = i >> 5, g = (i >> 3) & 3, jl = i & 7;
    g0_lds[i] = G0[t * G4 + g * HID + wg * 8 + jl];
  }
  __syncthreads();
  float cst = 0.f;
  for (int t = 0; t < steps; ++t) {
    // ---- wave 0: coherence-point poll of all 512 words (8 per lane) ----
    if (tid < 64) {
      unsigned long long* src = hb + (t & 1) * 512 + tid * 8;
      const unsigned tag = (unsigned)t;
      unsigned long long vv[8];
      int guard = 0;
      for (;;) {
        bool ok = true;
        #pragma unroll
        for (int i = 0; i < 8; ++i) vv[i] = atomicOr(&src[i], 0ULL);   // RMW-read at MALL
        #pragma unroll
        for (int i = 0; i < 8; ++i) ok = ok && ((unsigned)(vv[i] >> 32) == tag);
        if (__all(ok) || ++guard >= 16384) break;
        __builtin_amdgcn_s_sleep(1);
      }
      #pragma unroll
      for (int i = 0; i < 8; ++i) {
        union { unsigned u; float f; } c; c.u = (unsigned)vv[i];
        h_lds[tid * 8 + i] = c.f;
      }
    }
    __syncthreads();
    // lane covers k = lane*8 .. +8 for all 4 gates of its wave's j
    float hv[8];
    *(f32x4*)&hv[0] = *(const f32x4*)&h_lds[lane * 8];
    *(f32x4*)&hv[4] = *(const f32x4*)&h_lds[lane * 8 + 4];
    float p[4];
    #pragma unroll
    for (int g = 0; g < 4; ++g) {
      short8 wv = *(const short8*)&w_bf[((w * 4 + g) << 9) + (lane << 3)];
      float acc = 0.f;
      #pragma unroll
      for (int i = 0; i < 8; ++i)
        acc = fmaf(bf2f((unsigned short)wv[i]), hv[i], acc);
      p[g] = acc;
    }
    #pragma unroll
    for (int d = 1; d < 64; d <<= 1) {   // butterfly over 64 lanes (all lanes get sums)
      p[0] += __shfl_xor(p[0], d); p[1] += __shfl_xor(p[1], d);
      p[2] += __shfl_xor(p[2], d); p[3] += __shfl_xor(p[3], d);
    }
    float si = fast_sigmoid(g0_lds[t * 32 + 0 * 8 + w] + p[0]);
    float sf = fast_sigmoid(g0_lds[t * 32 + 1 * 8 + w] + p[1]);
    float gG = fast_tanh  (g0_lds[t * 32 + 2 * 8 + w] + p[2]);
    float so = fast_sigmoid(g0_lds[t * 32 + 3 * 8 + w] + p[3]);
    cst = sf * cst + si * gG;            // identical in all 64 lanes
    float hn = so * fast_tanh(cst);
    if (lane == 0) {
      union { float f; unsigned u; } hu; hu.f = hn;
      unsigned long long pack = ((unsigned long long)((unsigned)t + 1u) << 32) | (unsigned long long)hu.u;
      atomicExch(&hb[((t + 1) & 1) * 512 + j], pack);   // coherence-point publish (first!)
      hs[t * HID + j] = hn;
    }
  }
}

// ---------------- EWe_s / DWd_s projections (scaled by log2e) ----------------
__global__ __launch_bounds__(256) void kProj(const float* __restrict__ Weh,
                    const float* __restrict__ beh, float* __restrict__ ws) {
  int bid = blockIdx.x;                 // 0..190
  bool enc = bid < K_ENC;
  int row = enc ? bid : bid - K_ENC;
  const float* in = ws + (enc ? OFF_EENC : OFF_D) + row * HID;
  __shared__ float sin_[HID];
  int tid = threadIdx.x;
  sin_[tid] = in[tid]; sin_[tid + 256] = in[tid + 256];
  __syncthreads();
  if (tid < EMB) {
    const float* wr = Weh + tid * 1024 + (enc ? 0 : HID);
    float s = 0.f;
    #pragma unroll 4
    for (int h = 0; h < HID; ++h) s += sin_[h] * wr[h];
    if (!enc) s += beh[tid];
    ws[(enc ? OFF_EWE : OFF_DWD) + row * EMB + tid] = s * LOG2E;
  }
}

// ---------------- fused logits GEMM (bf16 MFMA) + online sum(2^s) ----------------
__global__ __launch_bounds__(256) void kLogits(float* __restrict__ ws) {
  const int t = blockIdx.x >> 2;
  const int chunk = blockIdx.x & 3;
  const int tid = threadIdx.x;
  const int lane = tid & 63;
  const int wv = tid >> 6;
  const int quad = lane >> 4, l15 = lane & 15;
  __shared__ __align__(16) unsigned short A[64 * 128];   // hpre_s bf16, [m][k] k-padded to 128
  const float* __restrict__ EWe = ws + OFF_EWE;
  const float* __restrict__ DWd = ws + OFF_DWD + t * EMB;
  for (int idx = tid; idx < 64 * 128; idx += 256) {
    int m = idx >> 7, k = idx & 127;
    float hv = 0.f;
    if (k < EMB) { float s = EWe[m * EMB + k] + DWd[k]; hv = s > 0.f ? s : 0.f; }
    A[idx] = f2bf(hv);
  }
  __syncthreads();
  short8 af[4][4];   // A fragments persistent in VGPRs: [mtile][kblock]
  #pragma unroll
  for (int mt = 0; mt < 4; ++mt)
    #pragma unroll
    for (int kb = 0; kb < 4; ++kb)
      af[mt][kb] = *(const short8*)&A[(mt * 16 + l15) * 128 + kb * 32 + quad * 8];
  const unsigned short* __restrict__ wem = (const unsigned short*)(ws + OFF_WEM);
  const float* __restrict__ bem_s = ws + OFF_BEM;
  float rs[4][4];
  #pragma unroll
  for (int a = 0; a < 4; ++a)
    #pragma unroll
    for (int b = 0; b < 4; ++b) rs[a][b] = 0.f;
  int vt = chunk * 500 + wv;
  short8 nb0, nb1, nb2, nb3; float nbi;
  nb0 = *(const short8*)&wem[(vt * 4 + 0) * 512 + lane * 8];
  nb1 = *(const short8*)&wem[(vt * 4 + 1) * 512 + lane * 8];
  nb2 = *(const short8*)&wem[(vt * 4 + 2) * 512 + lane * 8];
  nb3 = *(const short8*)&wem[(vt * 4 + 3) * 512 + lane * 8];
  nbi = bem_s[vt * 16 + l15];
  for (int ii = wv; ii < 500; ii += 4) {
    short8 cb0 = nb0, cb1 = nb1, cb2 = nb2, cb3 = nb3;
    float cbi = nbi;
    int nvt = vt + 4;
    if (ii + 4 < 500) {   // software pipeline next B tile
      nb0 = *(const short8*)&wem[(nvt * 4 + 0) * 512 + lane * 8];
      nb1 = *(const short8*)&wem[(nvt * 4 + 1) * 512 + lane * 8];
      nb2 = *(const short8*)&wem[(nvt * 4 + 2) * 512 + lane * 8];
      nb3 = *(const short8*)&wem[(nvt * 4 + 3) * 512 + lane * 8];
      nbi = bem_s[nvt * 16 + l15];
    }
    f32x4 acc[4];
    #pragma unroll
    for (int mt = 0; mt < 4; ++mt) acc[mt] = (f32x4){cbi, cbi, cbi, cbi};  // init with bem
    #pragma unroll
    for (int mt = 0; mt < 4; ++mt) {
      acc[mt] = __builtin_amdgcn_mfma_f32_16x16x32_bf16(af[mt][0], cb0, acc[mt], 0, 0, 0);
      acc[mt] = __builtin_amdgcn_mfma_f32_16x16x32_bf16(af[mt][1], cb1, acc[mt], 0, 0, 0);
      acc[mt] = __builtin_amdgcn_mfma_f32_16x16x32_bf16(af[mt][2], cb2, acc[mt], 0, 0, 0);
      acc[mt] = __builtin_amdgcn_mfma_f32_16x16x32_bf16(af[mt][3], cb3, acc[mt], 0, 0, 0);
    }
    #pragma unroll
    for (int mt = 0; mt < 4; ++mt)
      #pragma unroll
      for (int r = 0; r < 4; ++r)
        rs[mt][r] += __builtin_amdgcn_exp2f(acc[mt][r]);   // s already includes log2e scale
    vt = nvt;
  }
  // reduce across the 16 column-lanes of each quad, then one atomic per row
  #pragma unroll
  for (int d = 1; d < 16; d <<= 1)
    #pragma unroll
    for (int mt = 0; mt < 4; ++mt)
      #pragma unroll
      for (int r = 0; r < 4; ++r)
        rs[mt][r] += __shfl_xor(rs[mt][r], d);
  if (l15 == 0) {
    float* sum = ws + OFF_SUM + t * 64;
    #pragma unroll
    for (int mt = 0; mt < 4; ++mt)
      #pragma unroll
      for (int r = 0; r < 4; ++r)
        atomicAdd(&sum[mt * 16 + quad * 4 + r], rs[mt][r]);
  }
}

// ---------------- emission = ln2 * (s_word - log2(sum 2^s)), s_word in fp32 ----------------
__global__ __launch_bounds__(256) void kEmission(const int* __restrict__ y,
                    const float* __restrict__ Wem, float* __restrict__ ws) {
  int gid = blockIdx.x * 256 + threadIdx.x;
  if (gid >= 127 * 64) return;
  int t = gid >> 6, m = gid & 63;
  const float* ew = ws + OFF_EWE + m * EMB;
  const float* dw = ws + OFF_DWD + t * EMB;
  int wt = y[t + 1];
  const float* wr = Wem + wt * EMB;
  float s = ws[OFF_BEM + wt];
  #pragma unroll 4
  for (int e = 0; e < EMB; ++e) {
    float h = ew[e] + dw[e];
    h = h > 0.f ? h : 0.f;
    s += h * wr[e];
  }
  ws[OFF_EM + gid] = LN2 * (s - __builtin_amdgcn_logf(ws[OFF_SUM + gid]));
}

// ---------------- Viterbi: prefix-max trick + backtrace ----------------
// tranm[i][j] = fe + fs*(63-i-j) (i+j<64). scores[i][j] = q[i] + fe + fs*(63-j), q[i]=pa[i]-fs*i.
// flip cancels: new_pa[j] = P[j] + fe + fs*j + em[t][j]; ind'[j] = argP[j]  (P = prefix max of q).
__global__ __launch_bounds__(256) void kViterbi(const float* __restrict__ ws,
                                                float* __restrict__ out) {
  __shared__ float em_lds[127 * 64];
  __shared__ int   inds[128 * 64];
  __shared__ float sval;
  const int tid = threadIdx.x;
  for (int i = tid; i < 127 * 64; i += 256) em_lds[i] = ws[OFF_EM + i];
  if (tid < 64) inds[tid] = 0;   // indices row 0
  __syncthreads();
  if (tid < 64) {
    const int j = tid;
    const float fs = -0.4054651081081644f;   // log(128/192)
    const float fe = -1.0986122886681098f;   // log(64/192)
    float pa = 0.f;
    float emnext = em_lds[j];
    for (int t = 0; t < 127; ++t) {
      float emc = emnext;
      if (t < 126) emnext = em_lds[(t + 1) * 64 + j];
      float v = fmaf(-fs, (float)j, pa);   // q[j]
      int idx = j;
      #pragma unroll
      for (int d = 1; d < 64; d <<= 1) {   // inclusive prefix max, earliest argmax on ties
        float vv = __shfl_up(v, d);
        int   ii = __shfl_up(idx, d);
        bool cur = v > vv;                 // strict >: keep earlier index on ties
        v   = cur ? v : vv;
        idx = cur ? idx : ii;
      }
      pa = v + fe + fs * (float)j + emc;
      inds[(t + 1) * 64 + j] = idx;
    }
    if (j == 63) sval = pa;
  }
  __syncthreads();
  if (tid == 0) {
    int ind = 63;
    for (int t = 127; t >= 0; --t) {
      ind = inds[t * 64 + ind];
      out[t] = (float)ind;
    }
    out[128] = sval;
  }
}

extern "C" void kernel_launch(void* const* d_in, const int* in_sizes, int n_in,
                              void* d_out, int out_size, void* d_ws, size_t ws_size,
                              hipStream_t stream) {
  const int*   x    = (const int*)d_in[0];
  const int*   y    = (const int*)d_in[1];
  const float* emb  = (const float*)d_in[2];
  const float* eWih = (const float*)d_in[3];
  const float* eWhh = (const float*)d_in[4];
  const float* ebih = (const float*)d_in[5];
  const float* ebhh = (const float*)d_in[6];
  const float* dWih = (const float*)d_in[7];
  const float* dWhh = (const float*)d_in[8];
  const float* dbih = (const float*)d_in[9];
  const float* dbhh = (const float*)d_in[10];
  const float* Weh  = (const float*)d_in[11];
  const float* beh  = (const float*)d_in[12];
  const float* Wem  = (const float*)d_in[13];
  const float* bem  = (const float*)d_in[14];
  float* ws  = (float*)d_ws;
  float* out = (float*)d_out;

  hipLaunchKernelGGL(kZero,     dim3(49),   dim3(256), 0, stream, ws);
  hipLaunchKernelGGL(kG0,       dim3(1528), dim3(256), 0, stream, x, y, emb, eWih, ebih, ebhh, dWih, dbih, dbhh, ws);
  hipLaunchKernelGGL(kLstm,     dim3(256),  dim3(512), 0, stream, eWhh, dWhh, Wem, bem, ws);
  hipLaunchKernelGGL(kProj,     dim3(191),  dim3(256), 0, stream, Weh, beh, ws);
  hipLaunchKernelGGL(kLogits,   dim3(508),  dim3(256), 0, stream, ws);
  hipLaunchKernelGGL(kEmission, dim3(32),   dim3(256), 0, stream, y, Wem, ws);
  hipLaunchKernelGGL(kViterbi,  dim3(1),    dim3(256), 0, stream, ws, out);
}

// Round 9
// 699.563 us; speedup vs baseline: 1.2708x; 1.2708x over previous
//
#include <hip/hip_runtime.h>

// Seq2SeqWithAlignment: enc/dec LSTM -> hpre -> logits logsumexp -> Viterbi align.
// K=64 enc steps, T=128 dec tokens (127 dec steps used), H=512, E=100, V=32000.

#define K_ENC 64
#define HID   512
#define EMB   100
#define VOC   32000
#define G4    2048   // 4*HID

typedef __attribute__((ext_vector_type(8))) short  short8;
typedef __attribute__((ext_vector_type(4))) float  f32x4;

#define LOG2E 1.4426950408889634f
#define LN2   0.6931471805599453f

__device__ __forceinline__ unsigned short f2bf(float f) {
  union { float f; unsigned u; } x; x.f = f;
  unsigned r = x.u + 0x7FFFu + ((x.u >> 16) & 1u);  // RNE
  return (unsigned short)(r >> 16);
}
__device__ __forceinline__ float bf2f(unsigned short s) {
  union { unsigned u; float f; } x; x.u = ((unsigned)s) << 16; return x.f;
}

__device__ __forceinline__ float fast_sigmoid(float x) {
  return __builtin_amdgcn_rcpf(1.f + __builtin_amdgcn_exp2f(-LOG2E * x));
}
__device__ __forceinline__ float fast_tanh(float x) {
  return 1.f - 2.f * __builtin_amdgcn_rcpf(1.f + __builtin_amdgcn_exp2f(2.f * LOG2E * x));
}

// ---------------- workspace layout (float offsets) ----------------
#define OFF_HBUF  256       // u64[1024]: packed h channels [grp][slot][256], tag32|bf16|bf16
#define OFF_G0E   4352      // 64*2048  : enc Wih@x + bih + bhh
#define OFF_G0D   135424    // 127*2048 : dec
#define OFF_EENC  395520    // 64*512
#define OFF_D     428288    // 127*512
#define OFF_EWE   493312    // 64*100   : log2e * Eenc@We_E^T
#define OFF_DWD   499712    // 127*100  : log2e * (D@We_D^T + beh)
#define OFF_BEM   512412    // 32000    : log2e * bem
#define OFF_SUM   544412    // 127*64   : sum of 2^s over v (atomic)
#define OFF_EM    552540    // 127*64   : emission
#define OFF_WEM   560668    // ushort[4096000]: Wem bf16 in MFMA-B fragment-linear layout
// total ~10.4 MB

// ---------------- zero init (packed h channels => tag 0, sumexp) ----------------
__global__ void kZero(float* __restrict__ ws) {
  int gid = blockIdx.x * 256 + threadIdx.x;
  if (gid < 4352) ws[gid] = 0.f;
  else if (gid < 4352 + 127 * 64) ws[OFF_SUM + gid - 4352] = 0.f;
}

// ---------------- G0 = Wih @ emb[tok] + bih + bhh ----------------
__global__ __launch_bounds__(256) void kG0(const int* __restrict__ x, const int* __restrict__ y,
                    const float* __restrict__ emb,
                    const float* __restrict__ eWih, const float* __restrict__ ebih,
                    const float* __restrict__ ebhh,
                    const float* __restrict__ dWih, const float* __restrict__ dbih,
                    const float* __restrict__ dbhh,
                    float* __restrict__ ws) {
  int gid = blockIdx.x * 256 + threadIdx.x;
  const int enc_total = K_ENC * G4;
  if (gid >= enc_total + 127 * G4) return;
  bool enc = gid < enc_total;
  int loc = enc ? gid : gid - enc_total;
  int t = loc >> 11, r = loc & (G4 - 1);
  int tok = enc ? x[t] : y[t];
  const float* Wr = (enc ? eWih : dWih) + r * EMB;
  const float* er = emb + tok * EMB;
  float s = 0.f;
  #pragma unroll 4
  for (int e = 0; e < EMB; ++e) s += er[e] * Wr[e];
  s += enc ? (ebih[r] + ebhh[r]) : (dbih[r] + dbhh[r]);
  ws[(enc ? OFF_G0E : OFF_G0D) + t * G4 + r] = s;
}

// ---------------- Wem -> bf16 MFMA-B fragment-linear layout, bem scaled ----------------
__global__ __launch_bounds__(256) void kWemPrep(const float* __restrict__ Wem,
                    const float* __restrict__ bem, float* __restrict__ ws) {
  int gid = blockIdx.x * 256 + threadIdx.x;   // < 4096000
  int vt = gid >> 11;
  int kb = (gid >> 9) & 3;
  int L  = (gid >> 3) & 63;
  int j  = gid & 7;
  int v = vt * 16 + (L & 15);
  int k = kb * 32 + ((L >> 4) << 3) + j;
  float val = (k < EMB) ? Wem[v * EMB + k] : 0.f;
  ((unsigned short*)(ws + OFF_WEM))[gid] = f2bf(val);
  if (gid < VOC) ws[OFF_BEM + gid] = bem[gid] * LOG2E;
}

// ---------------- persistent LSTM: 32 WGs/group, 16 j/WG, LDS-resident bf16 weights ----
// Sync plane (R5-proven RMW + R9 packing): channel word = tag32 | bf16(h_even)<<16 |
// bf16(h_odd) -> 256 u64 per group-slot (HALF of R5/R8 traffic). Producer: lane0 of even
// jl packs its h with partner's (shfl_xor 32) and atomicExch (coherence point). Consumer:
// wave0 polls with atomicOr(ptr,0), per-lane done-masking (no re-RMW of matched words),
// s_sleep(2) backoff; unpacks to LDS; one __syncthreads.
// R8 lesson: poll cost ~ #WGs x words swept; 128 WGs x 512 words = 4.8us/step. This
// round: 64 WGs x 256 words + masking.
// Weights/G0/h all in dynamic LDS (~98KB, needs hipFuncSetAttribute): loop is global-free
// except the sync atomics. Poll BOUNDED (fails finite, never hangs).
__global__ __launch_bounds__(512, 1) void kLstm(const float* __restrict__ eWhh,
                    const float* __restrict__ dWhh, float* __restrict__ ws) {
  extern __shared__ __align__(16) char smem[];
  unsigned short* w_bf  = (unsigned short*)smem;              // [16j][4g][512k] bf16, 64KB
  float*          g0_l  = (float*)(smem + 65536);             // [t][g*16+jl], 127*64*4B
  float*          h_lds = (float*)(smem + 65536 + 32512);     // [32 chunks][20 pad], 2560B
  const int grp = blockIdx.x >> 5;            // 0=enc, 1=dec
  const int wg  = blockIdx.x & 31;
  const float* __restrict__ Whh = grp ? dWhh : eWhh;
  const float* __restrict__ G0  = ws + (grp ? OFF_G0D : OFF_G0E);
  float* __restrict__ hs = ws + (grp ? OFF_D : OFF_EENC);
  unsigned long long* hc = (unsigned long long*)(ws + OFF_HBUF) + grp * 512;  // [2][256]
  const int steps = grp ? 127 : K_ENC;
  const int tid = threadIdx.x;
  const int jl = tid >> 5, sub = tid & 31;
  const int j = wg * 16 + jl;                 // owned h index
  // preload weight slice bf16 and G0 slice
  for (int i = tid; i < 16 * 4 * 512; i += 512) {
    int pjl = i >> 11, g = (i >> 9) & 3, k = i & 511;
    w_bf[i] = f2bf(Whh[(g * HID + wg * 16 + pjl) * HID + k]);
  }
  for (int i = tid; i < steps * 64; i += 512) {
    int t = i >> 6, g = (i >> 4) & 3, pjl = i & 15;
    g0_l[i] = G0[t * G4 + g * HID + wg * 16 + pjl];
  }
  __syncthreads();
  float cst = 0.f;
  for (int t = 0; t < steps; ++t) {
    // ---- wave 0: masked coherence-point poll of 256 packed words (4/lane) ----
    if (tid < 64) {
      unsigned long long* src = hc + (t & 1) * 256 + tid * 4;
      const unsigned tag = (unsigned)t;
      unsigned long long vv[4];
      bool done0 = false, done1 = false, done2 = false, done3 = false;
      int guard = 0;
      for (;;) {
        if (!done0) { vv[0] = atomicOr(&src[0], 0ULL); done0 = ((unsigned)(vv[0] >> 32) == tag); }
        if (!done1) { vv[1] = atomicOr(&src[1], 0ULL); done1 = ((unsigned)(vv[1] >> 32) == tag); }
        if (!done2) { vv[2] = atomicOr(&src[2], 0ULL); done2 = ((unsigned)(vv[2] >> 32) == tag); }
        if (!done3) { vv[3] = atomicOr(&src[3], 0ULL); done3 = ((unsigned)(vv[3] >> 32) == tag); }
        bool all = done0 && done1 && done2 && done3;
        if (__all(all) || ++guard >= 16384) break;
        __builtin_amdgcn_s_sleep(2);
      }
      #pragma unroll
      for (int i = 0; i < 4; ++i) {           // word w=tid*4+i -> h[2w], h[2w+1]
        int k0 = tid * 8 + 2 * i;
        float he = bf2f((unsigned short)((vv[i] >> 16) & 0xFFFF));
        float ho = bf2f((unsigned short)(vv[i] & 0xFFFF));
        h_lds[((k0 >> 4) * 20) + (k0 & 15)]     = he;
        h_lds[(((k0+1) >> 4) * 20) + ((k0+1) & 15)] = ho;
      }
    }
    __syncthreads();
    // thread (jl, sub) covers k = sub*16..+16 for 4 gates of j
    float hk[16];
    #pragma unroll
    for (int q = 0; q < 4; ++q)
      *(f32x4*)&hk[q * 4] = *(const f32x4*)&h_lds[sub * 20 + q * 4];
    float p[4];
    #pragma unroll
    for (int g = 0; g < 4; ++g) {
      const unsigned short* wr = &w_bf[((jl * 4 + g) << 9) + (sub << 4)];
      short8 wv0 = *(const short8*)&wr[0];
      short8 wv1 = *(const short8*)&wr[8];
      float acc = 0.f;
      #pragma unroll
      for (int i = 0; i < 8; ++i) acc = fmaf(bf2f((unsigned short)wv0[i]), hk[i], acc);
      #pragma unroll
      for (int i = 0; i < 8; ++i) acc = fmaf(bf2f((unsigned short)wv1[i]), hk[8 + i], acc);
      p[g] = acc;
    }
    #pragma unroll
    for (int d = 1; d <= 16; d <<= 1) {       // reduce over 32 subs (stays in 32-half)
      p[0] += __shfl_xor(p[0], d); p[1] += __shfl_xor(p[1], d);
      p[2] += __shfl_xor(p[2], d); p[3] += __shfl_xor(p[3], d);
    }
    float si = fast_sigmoid(g0_l[t * 64 + 0 * 16 + jl] + p[0]);
    float sf = fast_sigmoid(g0_l[t * 64 + 1 * 16 + jl] + p[1]);
    float gG = fast_tanh  (g0_l[t * 64 + 2 * 16 + jl] + p[2]);
    float so = fast_sigmoid(g0_l[t * 64 + 3 * 16 + jl] + p[3]);
    cst = sf * cst + si * gG;                 // identical across the 32 subs
    float hn = so * fast_tanh(cst);
    float hp = __shfl_xor(hn, 32);            // partner jl^1's h (same wave: jl pairs)
    if (sub == 0) {
      if ((jl & 1) == 0) {                    // even jl publishes the (j, j+1) pair
        unsigned long long pack = ((unsigned long long)((unsigned)t + 1u) << 32)
                                | ((unsigned long long)f2bf(hn) << 16)
                                | (unsigned long long)f2bf(hp);
        atomicExch(&hc[((t + 1) & 1) * 256 + (j >> 1)], pack);  // publish first
      }
      hs[t * HID + j] = hn;                   // fp32 trace for downstream
    }
  }
}

// ---------------- EWe_s / DWd_s projections (scaled by log2e) ----------------
__global__ __launch_bounds__(256) void kProj(const float* __restrict__ Weh,
                    const float* __restrict__ beh, float* __restrict__ ws) {
  int bid = blockIdx.x;                 // 0..190
  bool enc = bid < K_ENC;
  int row = enc ? bid : bid - K_ENC;
  const float* in = ws + (enc ? OFF_EENC : OFF_D) + row * HID;
  __shared__ float sin_[HID];
  int tid = threadIdx.x;
  sin_[tid] = in[tid]; sin_[tid + 256] = in[tid + 256];
  __syncthreads();
  if (tid < EMB) {
    const float* wr = Weh + tid * 1024 + (enc ? 0 : HID);
    float s = 0.f;
    #pragma unroll 4
    for (int h = 0; h < HID; ++h) s += sin_[h] * wr[h];
    if (!enc) s += beh[tid];
    ws[(enc ? OFF_EWE : OFF_DWD) + row * EMB + tid] = s * LOG2E;
  }
}

// ---------------- fused logits GEMM (bf16 MFMA) + online sum(2^s) ----------------
__global__ __launch_bounds__(256) void kLogits(float* __restrict__ ws) {
  const int t = blockIdx.x >> 2;
  const int chunk = blockIdx.x & 3;
  const int tid = threadIdx.x;
  const int lane = tid & 63;
  const int wv = tid >> 6;
  const int quad = lane >> 4, l15 = lane & 15;
  __shared__ __align__(16) unsigned short A[64 * 128];   // hpre_s bf16, [m][k] k-padded to 128
  const float* __restrict__ EWe = ws + OFF_EWE;
  const float* __restrict__ DWd = ws + OFF_DWD + t * EMB;
  for (int idx = tid; idx < 64 * 128; idx += 256) {
    int m = idx >> 7, k = idx & 127;
    float hv = 0.f;
    if (k < EMB) { float s = EWe[m * EMB + k] + DWd[k]; hv = s > 0.f ? s : 0.f; }
    A[idx] = f2bf(hv);
  }
  __syncthreads();
  short8 af[4][4];   // A fragments persistent in VGPRs: [mtile][kblock]
  #pragma unroll
  for (int mt = 0; mt < 4; ++mt)
    #pragma unroll
    for (int kb = 0; kb < 4; ++kb)
      af[mt][kb] = *(const short8*)&A[(mt * 16 + l15) * 128 + kb * 32 + quad * 8];
  const unsigned short* __restrict__ wem = (const unsigned short*)(ws + OFF_WEM);
  const float* __restrict__ bem_s = ws + OFF_BEM;
  float rs[4][4];
  #pragma unroll
  for (int a = 0; a < 4; ++a)
    #pragma unroll
    for (int b = 0; b < 4; ++b) rs[a][b] = 0.f;
  int vt = chunk * 500 + wv;
  short8 nb0, nb1, nb2, nb3; float nbi;
  nb0 = *(const short8*)&wem[(vt * 4 + 0) * 512 + lane * 8];
  nb1 = *(const short8*)&wem[(vt * 4 + 1) * 512 + lane * 8];
  nb2 = *(const short8*)&wem[(vt * 4 + 2) * 512 + lane * 8];
  nb3 = *(const short8*)&wem[(vt * 4 + 3) * 512 + lane * 8];
  nbi = bem_s[vt * 16 + l15];
  for (int ii = wv; ii < 500; ii += 4) {
    short8 cb0 = nb0, cb1 = nb1, cb2 = nb2, cb3 = nb3;
    float cbi = nbi;
    int nvt = vt + 4;
    if (ii + 4 < 500) {   // software pipeline next B tile
      nb0 = *(const short8*)&wem[(nvt * 4 + 0) * 512 + lane * 8];
      nb1 = *(const short8*)&wem[(nvt * 4 + 1) * 512 + lane * 8];
      nb2 = *(const short8*)&wem[(nvt * 4 + 2) * 512 + lane * 8];
      nb3 = *(const short8*)&wem[(nvt * 4 + 3) * 512 + lane * 8];
      nbi = bem_s[nvt * 16 + l15];
    }
    f32x4 acc[4];
    #pragma unroll
    for (int mt = 0; mt < 4; ++mt) acc[mt] = (f32x4){cbi, cbi, cbi, cbi};  // init with bem
    #pragma unroll
    for (int mt = 0; mt < 4; ++mt) {
      acc[mt] = __builtin_amdgcn_mfma_f32_16x16x32_bf16(af[mt][0], cb0, acc[mt], 0, 0, 0);
      acc[mt] = __builtin_amdgcn_mfma_f32_16x16x32_bf16(af[mt][1], cb1, acc[mt], 0, 0, 0);
      acc[mt] = __builtin_amdgcn_mfma_f32_16x16x32_bf16(af[mt][2], cb2, acc[mt], 0, 0, 0);
      acc[mt] = __builtin_amdgcn_mfma_f32_16x16x32_bf16(af[mt][3], cb3, acc[mt], 0, 0, 0);
    }
    #pragma unroll
    for (int mt = 0; mt < 4; ++mt)
      #pragma unroll
      for (int r = 0; r < 4; ++r)
        rs[mt][r] += __builtin_amdgcn_exp2f(acc[mt][r]);   // s already includes log2e scale
    vt = nvt;
  }
  // reduce across the 16 column-lanes of each quad, then one atomic per row
  #pragma unroll
  for (int d = 1; d < 16; d <<= 1)
    #pragma unroll
    for (int mt = 0; mt < 4; ++mt)
      #pragma unroll
      for (int r = 0; r < 4; ++r)
        rs[mt][r] += __shfl_xor(rs[mt][r], d);
  if (l15 == 0) {
    float* sum = ws + OFF_SUM + t * 64;
    #pragma unroll
    for (int mt = 0; mt < 4; ++mt)
      #pragma unroll
      for (int r = 0; r < 4; ++r)
        atomicAdd(&sum[mt * 16 + quad * 4 + r], rs[mt][r]);
  }
}

// ---------------- emission = ln2 * (s_word - log2(sum 2^s)), s_word in fp32 ----------------
__global__ __launch_bounds__(256) void kEmission(const int* __restrict__ y,
                    const float* __restrict__ Wem, float* __restrict__ ws) {
  int gid = blockIdx.x * 256 + threadIdx.x;
  if (gid >= 127 * 64) return;
  int t = gid >> 6, m = gid & 63;
  const float* ew = ws + OFF_EWE + m * EMB;
  const float* dw = ws + OFF_DWD + t * EMB;
  int wt = y[t + 1];
  const float* wr = Wem + wt * EMB;
  float s = ws[OFF_BEM + wt];
  #pragma unroll 4
  for (int e = 0; e < EMB; ++e) {
    float h = ew[e] + dw[e];
    h = h > 0.f ? h : 0.f;
    s += h * wr[e];
  }
  ws[OFF_EM + gid] = LN2 * (s - __builtin_amdgcn_logf(ws[OFF_SUM + gid]));
}

// ---------------- Viterbi: prefix-max trick + backtrace ----------------
__global__ __launch_bounds__(256) void kViterbi(const float* __restrict__ ws,
                                                float* __restrict__ out) {
  __shared__ float em_lds[127 * 64];
  __shared__ int   inds[128 * 64];
  __shared__ float sval;
  const int tid = threadIdx.x;
  for (int i = tid; i < 127 * 64; i += 256) em_lds[i] = ws[OFF_EM + i];
  if (tid < 64) inds[tid] = 0;   // indices row 0
  __syncthreads();
  if (tid < 64) {
    const int j = tid;
    const float fs = -0.4054651081081644f;   // log(128/192)
    const float fe = -1.0986122886681098f;   // log(64/192)
    float pa = 0.f;
    float emnext = em_lds[j];
    for (int t = 0; t < 127; ++t) {
      float emc = emnext;
      if (t < 126) emnext = em_lds[(t + 1) * 64 + j];
      float v = fmaf(-fs, (float)j, pa);   // q[j]
      int idx = j;
      #pragma unroll
      for (int d = 1; d < 64; d <<= 1) {   // inclusive prefix max, earliest argmax on ties
        float vv = __shfl_up(v, d);
        int   ii = __shfl_up(idx, d);
        bool cur = v > vv;                 // strict >: keep earlier index on ties
        v   = cur ? v : vv;
        idx = cur ? idx : ii;
      }
      pa = v + fe + fs * (float)j + emc;
      inds[(t + 1) * 64 + j] = idx;
    }
    if (j == 63) sval = pa;
  }
  __syncthreads();
  if (tid == 0) {
    int ind = 63;
    for (int t = 127; t >= 0; --t) {
      ind = inds[t * 64 + ind];
      out[t] = (float)ind;
    }
    out[128] = sval;
  }
}

extern "C" void kernel_launch(void* const* d_in, const int* in_sizes, int n_in,
                              void* d_out, int out_size, void* d_ws, size_t ws_size,
                              hipStream_t stream) {
  const int*   x    = (const int*)d_in[0];
  const int*   y    = (const int*)d_in[1];
  const float* emb  = (const float*)d_in[2];
  const float* eWih = (const float*)d_in[3];
  const float* eWhh = (const float*)d_in[4];
  const float* ebih = (const float*)d_in[5];
  const float* ebhh = (const float*)d_in[6];
  const float* dWih = (const float*)d_in[7];
  const float* dWhh = (const float*)d_in[8];
  const float* dbih = (const float*)d_in[9];
  const float* dbhh = (const float*)d_in[10];
  const float* Weh  = (const float*)d_in[11];
  const float* beh  = (const float*)d_in[12];
  const float* Wem  = (const float*)d_in[13];
  const float* bem  = (const float*)d_in[14];
  float* ws  = (float*)d_ws;
  float* out = (float*)d_out;

  const int lstm_lds = 65536 + 32512 + 2560;   // weights + g0 + h = 100608 B
  hipFuncSetAttribute((const void*)kLstm, hipFuncAttributeMaxDynamicSharedMemorySize, lstm_lds);

  hipLaunchKernelGGL(kZero,     dim3(49),    dim3(256), 0, stream, ws);
  hipLaunchKernelGGL(kG0,       dim3(1528),  dim3(256), 0, stream, x, y, emb, eWih, ebih, ebhh, dWih, dbih, dbhh, ws);
  hipLaunchKernelGGL(kWemPrep,  dim3(16000), dim3(256), 0, stream, Wem, bem, ws);
  hipLaunchKernelGGL(kLstm,     dim3(64),    dim3(512), lstm_lds, stream, eWhh, dWhh, ws);
  hipLaunchKernelGGL(kProj,     dim3(191),   dim3(256), 0, stream, Weh, beh, ws);
  hipLaunchKernelGGL(kLogits,   dim3(508),   dim3(256), 0, stream, ws);
  hipLaunchKernelGGL(kEmission, dim3(32),    dim3(256), 0, stream, y, Wem, ws);
  hipLaunchKernelGGL(kViterbi,  dim3(1),     dim3(256), 0, stream, ws, out);
}